// Round 15
// baseline (88.326 us; speedup 1.0000x reference)
//
#include <hip/hip_runtime.h>
#include <hip/hip_fp16.h>
#include <math.h>

#define N_NODES 30000
#define MAXN 32
#define DIM 128
#define NHEAD 4
#define HDIM 32
#define LN_EPS 1e-5f

typedef _Float16 f16;
typedef unsigned char uchar;
typedef __attribute__((ext_vector_type(8))) _Float16 f16x8;
typedef __attribute__((ext_vector_type(4))) float f32x4;
typedef __attribute__((ext_vector_type(2))) float f32x2;

static __device__ __forceinline__ __half2 as_h2(uint u) { return __builtin_bit_cast(__half2, u); }
static __device__ __forceinline__ uint as_u(__half2 h) { return __builtin_bit_cast(uint, h); }
static __device__ __forceinline__ f16x8 as_f16x8(uint4 u) { return __builtin_bit_cast(f16x8, u); }

// async global->LDS gather, 16B per lane; dest = uniform base + lane*16
static __device__ __forceinline__ void async_ld16(const uint* g, uint* lds_base) {
    __builtin_amdgcn_global_load_lds(
        (const __attribute__((address_space(1))) void*)g,
        (__attribute__((address_space(3))) void*)lds_base,
        16, 0, 0);
}

// ---------------- prep: W[k][n] f32 -> WT[n][k] f16 for Wq,Wk,Wv,Wfc ----------------
__global__ __launch_bounds__(128) void prep_kernel(
    const float* __restrict__ Wq, const float* __restrict__ Wk,
    const float* __restrict__ Wv, const float* __restrict__ Wfc,
    f16* __restrict__ WqT, f16* __restrict__ WkT,
    f16* __restrict__ WvT, f16* __restrict__ WfcT)
{
    const int n = blockIdx.x, k = threadIdx.x;
    WqT[n * DIM + k]  = (f16)Wq[k * DIM + n];
    WkT[n * DIM + k]  = (f16)Wk[k * DIM + n];
    WvT[n * DIM + k]  = (f16)Wv[k * DIM + n];
    WfcT[n * DIM + k] = (f16)Wfc[k * DIM + n];
}

// ---------------- Kernel 1: QKV projection via MFMA, weights staged in LDS ----------------
// Q,K -> fp16; V -> fp8 e4m3 (halves gather bytes + LDS staging footprint).
__global__ __launch_bounds__(256) void qkv_mfma_kernel(
    const float* __restrict__ h,
    const f16* __restrict__ WqT,
    const f16* __restrict__ WkT,
    const f16* __restrict__ WvT,
    f16* __restrict__ Qout,
    f16* __restrict__ Kout,
    uchar* __restrict__ Vout8)
{
    __shared__ f16 wlds[DIM][136];

    const int lane = threadIdx.x & 63;
    const int wid  = threadIdx.x >> 6;
    const int r0w  = blockIdx.x * 64 + wid * 16;
    const int rl = lane & 15;
    const int kb = lane >> 4;

    const int arow = min(r0w + rl, N_NODES - 1);
    const float* hrow = h + (size_t)arow * DIM + kb * 8;
    f16x8 a[4];
#pragma unroll
    for (int ks = 0; ks < 4; ++ks) {
        float4 f0 = *(const float4*)(hrow + ks * 32);
        float4 f1 = *(const float4*)(hrow + ks * 32 + 4);
        f16x8 v;
        v[0] = (f16)f0.x; v[1] = (f16)f0.y; v[2] = (f16)f0.z; v[3] = (f16)f0.w;
        v[4] = (f16)f1.x; v[5] = (f16)f1.y; v[6] = (f16)f1.z; v[7] = (f16)f1.w;
        a[ks] = v;
    }

    f32x4 acc[8];

#define STAGE_W(WT)                                                         \
    {                                                                       \
        const uint4* s4 = (const uint4*)(WT);                               \
        _Pragma("unroll")                                                   \
        for (int i = 0; i < 8; ++i) {                                       \
            int L = i * 256 + (int)threadIdx.x;                             \
            *(uint4*)(&wlds[L >> 4][(L & 15) * 8]) = s4[L];                 \
        }                                                                   \
    }

#define GEMM_LDS()                                                          \
    _Pragma("unroll")                                                       \
    for (int tc = 0; tc < 8; ++tc) acc[tc] = (f32x4){0.f, 0.f, 0.f, 0.f};   \
    _Pragma("unroll")                                                       \
    for (int ks = 0; ks < 4; ++ks) {                                        \
        _Pragma("unroll")                                                   \
        for (int tc = 0; tc < 8; ++tc) {                                    \
            f16x8 bfrag = *(const f16x8*)(&wlds[rl + 16 * tc][ks * 32 + kb * 8]); \
            acc[tc] = __builtin_amdgcn_mfma_f32_16x16x32_f16(a[ks], bfrag, acc[tc], 0, 0, 0); \
        }                                                                   \
    }

#define STORE_F16(OUT)                                                      \
    _Pragma("unroll")                                                       \
    for (int j = 0; j < 4; ++j) {                                           \
        const int row = r0w + kb * 4 + j;                                   \
        if (row < N_NODES) {                                                \
            f16* orow = (OUT) + (size_t)row * DIM;                          \
            _Pragma("unroll")                                               \
            for (int tc = 0; tc < 8; ++tc) orow[rl + 16 * tc] = (f16)acc[tc][j]; \
        }                                                                   \
    }

    STAGE_W(WqT);
    __syncthreads();
    GEMM_LDS();
    STORE_F16(Qout);
    __syncthreads();
    STAGE_W(WkT);
    __syncthreads();
    GEMM_LDS();
    STORE_F16(Kout);
    __syncthreads();
    STAGE_W(WvT);
    __syncthreads();
    GEMM_LDS();
    // V: fp8 e4m3 store
#pragma unroll
    for (int j = 0; j < 4; ++j) {
        const int row = r0w + kb * 4 + j;
        if (row < N_NODES) {
            uchar* orow = Vout8 + (size_t)row * DIM;
#pragma unroll
            for (int tc = 0; tc < 8; ++tc) {
                uint r = (uint)__builtin_amdgcn_cvt_pk_fp8_f32(acc[tc][j], 0.f, 0, false);
                orow[rl + 16 * tc] = (uchar)(r & 0xffu);
            }
        }
    }
}

// ---------------- Kernel 2: fused gather-attention + FC + GELU + LN ----------------
// 512 threads = 8 waves = 8 nodes (1 node/wave). LDS < 40KB -> 4 blocks/CU.
// K: 8 uint4 direct (fp16, regs). V: fp8, 4 async global_load_lds per node.
// Q read direct from global (L1 broadcast); idx via __shfl; al/fcout share LDS.
__global__ __launch_bounds__(512, 8) void attn_fc_kernel(
    const f16* __restrict__ Qh,          // [N][128] fp16 (ws)
    const f16* __restrict__ Kh,
    const uchar* __restrict__ V8,        // [N][128] fp8 e4m3 (ws)
    const int* __restrict__ nidx,
    const int* __restrict__ nmask,
    const f16* __restrict__ WfcT,        // [n][k] fp16
    const float* __restrict__ bfc,
    const float* __restrict__ gamma,
    const float* __restrict__ beta,
    float* __restrict__ out)
{
    __shared__ uint  vlds8[8][1024];      // 32KB: V fp8 [node][32 rows x 128B]
    __shared__ uint  rv_u[8][68];         // attn-out rows as half2      (2.2KB)
    __shared__ float ufc[8][132];         // union: alpha [hh*33+m] during PV,
                                          //        FC output after barrier (4.2KB)

    const int t    = threadIdx.x;
    const int b    = blockIdx.x;
    const int w    = t >> 6;        // wave = node slot 0..7
    const int lane = t & 63;
    const int node = b * 8 + w;

    // ---- front-load independent memory ops ----
    const int m   = lane & 31;
    const int hh2 = lane >> 5;
    const int src = nidx[(size_t)node * MAXN + m];
    const int msk = nmask[(size_t)node * MAXN + m];

    // K loads (issued FIRST -> oldest in vmcnt queue)
    const uint4* kr0 = (const uint4*)(Kh + (size_t)src * DIM + hh2 * HDIM);
    const uint4* kr1 = (const uint4*)(Kh + (size_t)src * DIM + (hh2 + 2) * HDIM);
    uint4 k00 = kr0[0], k01 = kr0[1], k02 = kr0[2], k03 = kr0[3];
    uint4 k10 = kr1[0], k11 = kr1[1], k12 = kr1[2], k13 = kr1[3];

    // V async staging (fp8): instr i covers rows i*8+(lane>>3), chunk lane&7.
    // neighbor index via shfl (lane r holds idx for m=r).
    {
#pragma unroll
        for (int i = 0; i < 4; ++i) {
            int r = i * 8 + (lane >> 3);
            int srcR = __shfl(src, r);
            const uint* gp = (const uint*)(V8 + (size_t)srcR * DIM + (lane & 7) * 16);
            async_ld16(gp, &vlds8[w][i * 256]);
        }
    }

    // ---- scores (Q direct from global: same-addr per 32-group -> L1 broadcast) ----
    float sc[2];
    {
        const uint4* qg = (const uint4*)(Qh + (size_t)node * DIM + hh2 * HDIM);
        uint4 q0 = qg[0], q1 = qg[1], q2 = qg[2], q3 = qg[3];
        __half2 a2 = as_h2(0u);
        a2 = __hfma2(as_h2(q0.x), as_h2(k00.x), a2);
        a2 = __hfma2(as_h2(q0.y), as_h2(k00.y), a2);
        a2 = __hfma2(as_h2(q0.z), as_h2(k00.z), a2);
        a2 = __hfma2(as_h2(q0.w), as_h2(k00.w), a2);
        a2 = __hfma2(as_h2(q1.x), as_h2(k01.x), a2);
        a2 = __hfma2(as_h2(q1.y), as_h2(k01.y), a2);
        a2 = __hfma2(as_h2(q1.z), as_h2(k01.z), a2);
        a2 = __hfma2(as_h2(q1.w), as_h2(k01.w), a2);
        a2 = __hfma2(as_h2(q2.x), as_h2(k02.x), a2);
        a2 = __hfma2(as_h2(q2.y), as_h2(k02.y), a2);
        a2 = __hfma2(as_h2(q2.z), as_h2(k02.z), a2);
        a2 = __hfma2(as_h2(q2.w), as_h2(k02.w), a2);
        a2 = __hfma2(as_h2(q3.x), as_h2(k03.x), a2);
        a2 = __hfma2(as_h2(q3.y), as_h2(k03.y), a2);
        a2 = __hfma2(as_h2(q3.z), as_h2(k03.z), a2);
        a2 = __hfma2(as_h2(q3.w), as_h2(k03.w), a2);
        float acc = __half2float(__low2half(a2)) + __half2float(__high2half(a2));
        sc[0] = (msk == 0) ? -1e9f : acc * 0.17677669529663687f;
    }
    {
        const uint4* qg = (const uint4*)(Qh + (size_t)node * DIM + (hh2 + 2) * HDIM);
        uint4 q0 = qg[0], q1 = qg[1], q2 = qg[2], q3 = qg[3];
        __half2 a2 = as_h2(0u);
        a2 = __hfma2(as_h2(q0.x), as_h2(k10.x), a2);
        a2 = __hfma2(as_h2(q0.y), as_h2(k10.y), a2);
        a2 = __hfma2(as_h2(q0.z), as_h2(k10.z), a2);
        a2 = __hfma2(as_h2(q0.w), as_h2(k10.w), a2);
        a2 = __hfma2(as_h2(q1.x), as_h2(k11.x), a2);
        a2 = __hfma2(as_h2(q1.y), as_h2(k11.y), a2);
        a2 = __hfma2(as_h2(q1.z), as_h2(k11.z), a2);
        a2 = __hfma2(as_h2(q1.w), as_h2(k11.w), a2);
        a2 = __hfma2(as_h2(q2.x), as_h2(k12.x), a2);
        a2 = __hfma2(as_h2(q2.y), as_h2(k12.y), a2);
        a2 = __hfma2(as_h2(q2.z), as_h2(k12.z), a2);
        a2 = __hfma2(as_h2(q2.w), as_h2(k12.w), a2);
        a2 = __hfma2(as_h2(q3.x), as_h2(k13.x), a2);
        a2 = __hfma2(as_h2(q3.y), as_h2(k13.y), a2);
        a2 = __hfma2(as_h2(q3.z), as_h2(k13.z), a2);
        a2 = __hfma2(as_h2(q3.w), as_h2(k13.w), a2);
        float acc = __half2float(__low2half(a2)) + __half2float(__high2half(a2));
        sc[1] = (msk == 0) ? -1e9f : acc * 0.17677669529663687f;
    }

    // ---- softmax over m (32-lane groups); alpha -> union LDS ----
#pragma unroll
    for (int hp = 0; hp < 2; ++hp) {
        float mx = sc[hp];
#pragma unroll
        for (int off = 1; off < 32; off <<= 1)
            mx = fmaxf(mx, __shfl_xor(mx, off));
        float e = __expf(sc[hp] - mx);
        float s = e;
#pragma unroll
        for (int off = 1; off < 32; off <<= 1)
            s += __shfl_xor(s, off);
        ufc[w][(hh2 + 2 * hp) * 33 + m] = e / s;
    }

    // ---- wait V staging, then PV from LDS (fp8 -> f32); lane = dim-pair ----
    asm volatile("s_waitcnt vmcnt(0)" ::: "memory");
    {
        const int hh = lane >> 4;            // head of dims 2*lane, 2*lane+1
        const uint sh = (lane & 1) ? 16u : 0u;
        float a0 = 0.f, a1 = 0.f;
#pragma unroll
        for (int mm = 0; mm < MAXN; ++mm) {
            uint u = vlds8[w][mm * 32 + (lane >> 1)];
            f32x2 vf = __builtin_amdgcn_cvt_pk_f32_fp8(u >> sh, false);
            float al = ufc[w][hh * 33 + mm];
            a0 = fmaf(al, vf.x, a0);
            a1 = fmaf(al, vf.y, a1);
        }
        rv_u[w][lane] = as_u(__floats2half2_rn(a0, a1));
    }
    __syncthreads();     // all alpha reads done; ufc may now be reused as fcout

    // ---- FC via MFMA; wave w = column tile w (8 real rows, 8 zero) ----
    {
        const int rl  = lane & 15;
        const int kb  = lane >> 4;
        const int col = 16 * w + rl;

        f32x4 acc = (f32x4){0.f, 0.f, 0.f, 0.f};
#pragma unroll
        for (int ks = 0; ks < 4; ++ks) {
            uint4 au = *(const uint4*)(&rv_u[rl & 7][ks * 16 + kb * 4]);
            if (rl >= 8) au = (uint4){0u, 0u, 0u, 0u};
            f16x8 af = as_f16x8(au);
            f16x8 bfr = *(const f16x8*)(WfcT + (size_t)col * DIM + ks * 32 + kb * 8);
            acc = __builtin_amdgcn_mfma_f32_16x16x32_f16(af, bfr, acc, 0, 0, 0);
        }
        if (kb < 2) {
#pragma unroll
            for (int j = 0; j < 4; ++j) ufc[kb * 4 + j][col] = acc[j];
        }
    }
    __syncthreads();

    // ---- epilogue (wave-local): wave w = node w; 2 cols/lane; in-wave LN ----
    {
        float g2[2];
        float s1 = 0.f, s2 = 0.f;
#pragma unroll
        for (int p = 0; p < 2; ++p) {
            const int c = lane + 64 * p;
            float qv = (float)Qh[(size_t)node * DIM + c];
            float x = ufc[w][c] + bfc[c] + qv;
            float gg = 0.5f * x * (1.0f + erff(x * 0.70710678118654752f));
            g2[p] = gg;
            s1 += gg;
            s2 += gg * gg;
        }
#pragma unroll
        for (int off = 1; off < 64; off <<= 1) {
            s1 += __shfl_xor(s1, off);
            s2 += __shfl_xor(s2, off);
        }
        float mean = s1 * (1.0f / DIM);
        float var  = s2 * (1.0f / DIM) - mean * mean;
        float invs = rsqrtf(var + LN_EPS);
#pragma unroll
        for (int p = 0; p < 2; ++p) {
            const int c = lane + 64 * p;
            out[(size_t)node * DIM + c] = (g2[p] - mean) * invs * gamma[c] + beta[c];
        }
    }
}

extern "C" void kernel_launch(void* const* d_in, const int* in_sizes, int n_in,
                              void* d_out, int out_size, void* d_ws, size_t ws_size,
                              hipStream_t stream) {
    (void)in_sizes; (void)n_in; (void)out_size; (void)ws_size;
    const float* h     = (const float*)d_in[0];
    const float* Wq    = (const float*)d_in[1];
    const float* Wk    = (const float*)d_in[2];
    const float* Wv    = (const float*)d_in[3];
    const float* Wfc   = (const float*)d_in[4];
    const float* bfc   = (const float*)d_in[5];
    const float* gamma = (const float*)d_in[6];
    const float* beta  = (const float*)d_in[7];
    const int* nidx    = (const int*)d_in[8];
    const int* nmask   = (const int*)d_in[9];

    f16*   Kh   = (f16*)d_ws;
    f16*   Qh   = Kh + (size_t)N_NODES * DIM;
    uchar* V8   = (uchar*)(Qh + (size_t)N_NODES * DIM);
    f16*   WqT  = (f16*)(V8 + (size_t)N_NODES * DIM);
    f16*   WkT  = WqT + (size_t)DIM * DIM;
    f16*   WvT  = WkT + (size_t)DIM * DIM;
    f16*   WfcT = WvT + (size_t)DIM * DIM;

    prep_kernel<<<DIM, DIM, 0, stream>>>(Wq, Wk, Wv, Wfc, WqT, WkT, WvT, WfcT);
    qkv_mfma_kernel<<<(N_NODES + 63) / 64, 256, 0, stream>>>(h, WqT, WkT, WvT, Qh, Kh, V8);
    attn_fc_kernel<<<N_NODES / 8, 512, 0, stream>>>(Qh, Kh, V8, nidx, nmask,
                                                    WfcT, bfc, gamma, beta, (float*)d_out);
}

// Round 16
// 85.225 us; speedup vs baseline: 1.0364x; 1.0364x over previous
//
#include <hip/hip_runtime.h>
#include <hip/hip_fp16.h>
#include <math.h>

#define N_NODES 30000
#define MAXN 32
#define DIM 128
#define NHEAD 4
#define HDIM 32
#define LN_EPS 1e-5f

typedef _Float16 f16;
typedef unsigned char uchar;
typedef __attribute__((ext_vector_type(8))) _Float16 f16x8;
typedef __attribute__((ext_vector_type(4))) float f32x4;
typedef __attribute__((ext_vector_type(2))) float f32x2;

static __device__ __forceinline__ __half2 as_h2(uint u) { return __builtin_bit_cast(__half2, u); }
static __device__ __forceinline__ uint as_u(__half2 h) { return __builtin_bit_cast(uint, h); }
static __device__ __forceinline__ f16x8 as_f16x8(uint4 u) { return __builtin_bit_cast(f16x8, u); }

// async global->LDS gather, 16B per lane; dest = uniform base + lane*16
static __device__ __forceinline__ void async_ld16(const uint* g, uint* lds_base) {
    __builtin_amdgcn_global_load_lds(
        (const __attribute__((address_space(1))) void*)g,
        (__attribute__((address_space(3))) void*)lds_base,
        16, 0, 0);
}

// ---------------- prep: W[k][n] f32 -> WT[n][k] f16 for Wq,Wk,Wv,Wfc ----------------
__global__ __launch_bounds__(128) void prep_kernel(
    const float* __restrict__ Wq, const float* __restrict__ Wk,
    const float* __restrict__ Wv, const float* __restrict__ Wfc,
    f16* __restrict__ WqT, f16* __restrict__ WkT,
    f16* __restrict__ WvT, f16* __restrict__ WfcT)
{
    const int n = blockIdx.x, k = threadIdx.x;
    WqT[n * DIM + k]  = (f16)Wq[k * DIM + n];
    WkT[n * DIM + k]  = (f16)Wk[k * DIM + n];
    WvT[n * DIM + k]  = (f16)Wv[k * DIM + n];
    WfcT[n * DIM + k] = (f16)Wfc[k * DIM + n];
}

// ---------------- Kernel 1: QKV projection via MFMA, weights staged in LDS ----------------
// Q,K -> fp16; V -> fp8 e4m3.
__global__ __launch_bounds__(256) void qkv_mfma_kernel(
    const float* __restrict__ h,
    const f16* __restrict__ WqT,
    const f16* __restrict__ WkT,
    const f16* __restrict__ WvT,
    f16* __restrict__ Qout,
    f16* __restrict__ Kout,
    uchar* __restrict__ Vout8)
{
    __shared__ f16 wlds[DIM][136];

    const int lane = threadIdx.x & 63;
    const int wid  = threadIdx.x >> 6;
    const int r0w  = blockIdx.x * 64 + wid * 16;
    const int rl = lane & 15;
    const int kb = lane >> 4;

    const int arow = min(r0w + rl, N_NODES - 1);
    const float* hrow = h + (size_t)arow * DIM + kb * 8;
    f16x8 a[4];
#pragma unroll
    for (int ks = 0; ks < 4; ++ks) {
        float4 f0 = *(const float4*)(hrow + ks * 32);
        float4 f1 = *(const float4*)(hrow + ks * 32 + 4);
        f16x8 v;
        v[0] = (f16)f0.x; v[1] = (f16)f0.y; v[2] = (f16)f0.z; v[3] = (f16)f0.w;
        v[4] = (f16)f1.x; v[5] = (f16)f1.y; v[6] = (f16)f1.z; v[7] = (f16)f1.w;
        a[ks] = v;
    }

    f32x4 acc[8];

#define STAGE_W(WT)                                                         \
    {                                                                       \
        const uint4* s4 = (const uint4*)(WT);                               \
        _Pragma("unroll")                                                   \
        for (int i = 0; i < 8; ++i) {                                       \
            int L = i * 256 + (int)threadIdx.x;                             \
            *(uint4*)(&wlds[L >> 4][(L & 15) * 8]) = s4[L];                 \
        }                                                                   \
    }

#define GEMM_LDS()                                                          \
    _Pragma("unroll")                                                       \
    for (int tc = 0; tc < 8; ++tc) acc[tc] = (f32x4){0.f, 0.f, 0.f, 0.f};   \
    _Pragma("unroll")                                                       \
    for (int ks = 0; ks < 4; ++ks) {                                        \
        _Pragma("unroll")                                                   \
        for (int tc = 0; tc < 8; ++tc) {                                    \
            f16x8 bfrag = *(const f16x8*)(&wlds[rl + 16 * tc][ks * 32 + kb * 8]); \
            acc[tc] = __builtin_amdgcn_mfma_f32_16x16x32_f16(a[ks], bfrag, acc[tc], 0, 0, 0); \
        }                                                                   \
    }

#define STORE_F16(OUT)                                                      \
    _Pragma("unroll")                                                       \
    for (int j = 0; j < 4; ++j) {                                           \
        const int row = r0w + kb * 4 + j;                                   \
        if (row < N_NODES) {                                                \
            f16* orow = (OUT) + (size_t)row * DIM;                          \
            _Pragma("unroll")                                               \
            for (int tc = 0; tc < 8; ++tc) orow[rl + 16 * tc] = (f16)acc[tc][j]; \
        }                                                                   \
    }

    STAGE_W(WqT);
    __syncthreads();
    GEMM_LDS();
    STORE_F16(Qout);
    __syncthreads();
    STAGE_W(WkT);
    __syncthreads();
    GEMM_LDS();
    STORE_F16(Kout);
    __syncthreads();
    STAGE_W(WvT);
    __syncthreads();
    GEMM_LDS();
    // V: fp8 e4m3 store
#pragma unroll
    for (int j = 0; j < 4; ++j) {
        const int row = r0w + kb * 4 + j;
        if (row < N_NODES) {
            uchar* orow = Vout8 + (size_t)row * DIM;
#pragma unroll
            for (int tc = 0; tc < 8; ++tc) {
                uint r = (uint)__builtin_amdgcn_cvt_pk_fp8_f32(acc[tc][j], 0.f, 0, false);
                orow[rl + 16 * tc] = (uchar)(r & 0xffu);
            }
        }
    }
}

// ---------------- Kernel 2: fused gather-attention + FC + GELU + LN ----------------
// 512 threads = 8 waves = 8 nodes (1 node/wave). LDS 39.2KB -> 4 blocks/CU.
// vmcnt discipline: Q load oldest, K next, V staging youngest -> scores wait
// leaves V in flight. qsh/rv_u share LDS (wave-local lifetimes); al/fcout share LDS.
__global__ __launch_bounds__(512, 8) void attn_fc_kernel(
    const f16* __restrict__ Qh,          // [N][128] fp16 (ws)
    const f16* __restrict__ Kh,
    const uchar* __restrict__ V8,        // [N][128] fp8 e4m3 (ws)
    const int* __restrict__ nidx,
    const int* __restrict__ nmask,
    const f16* __restrict__ WfcT,        // [n][k] fp16
    const float* __restrict__ bfc,
    const float* __restrict__ gamma,
    const float* __restrict__ beta,
    float* __restrict__ out)
{
    __shared__ uint  vlds8[8][1024];      // 32KB: V fp8 [node][32 rows x 128B]
    __shared__ uint  qrv[8][68];          // union: Q row (scores) -> attn-out (PV/FC)
    __shared__ float ufc[8][132];         // union: alpha [hh*33+m] -> FC output

    const int t    = threadIdx.x;
    const int b    = blockIdx.x;
    const int w    = t >> 6;        // wave = node slot 0..7
    const int lane = t & 63;
    const int node = b * 8 + w;

    // ---- front-load independent memory ops (Q oldest, then K, then V async) ----
    const int m   = lane & 31;
    const int hh2 = lane >> 5;
    const int src = nidx[(size_t)node * MAXN + m];
    const int msk = nmask[(size_t)node * MAXN + m];

    // Q row -> LDS (global load issued first = oldest in vmem queue)
    qrv[w][lane] = ((const uint*)Qh)[(size_t)node * 64 + lane];

    // K loads (next oldest; consumed by scores)
    const uint4* kr0 = (const uint4*)(Kh + (size_t)src * DIM + hh2 * HDIM);
    const uint4* kr1 = (const uint4*)(Kh + (size_t)src * DIM + (hh2 + 2) * HDIM);
    uint4 k00 = kr0[0], k01 = kr0[1], k02 = kr0[2], k03 = kr0[3];
    uint4 k10 = kr1[0], k11 = kr1[1], k12 = kr1[2], k13 = kr1[3];

    // V async staging (fp8, youngest): instr i covers rows i*8+(lane>>3), chunk lane&7.
    {
#pragma unroll
        for (int i = 0; i < 4; ++i) {
            int r = i * 8 + (lane >> 3);
            int srcR = __shfl(src, r);
            const uint* gp = (const uint*)(V8 + (size_t)srcR * DIM + (lane & 7) * 16);
            async_ld16(gp, &vlds8[w][i * 256]);
        }
    }

    // ---- scores (Q from LDS, K from regs; V staging stays in flight) ----
    float sc[2];
    {
        const uint4* qr = (const uint4*)(&qrv[w][hh2 * 16]);
        uint4 q0 = qr[0], q1 = qr[1], q2 = qr[2], q3 = qr[3];
        __half2 a2 = as_h2(0u);
        a2 = __hfma2(as_h2(q0.x), as_h2(k00.x), a2);
        a2 = __hfma2(as_h2(q0.y), as_h2(k00.y), a2);
        a2 = __hfma2(as_h2(q0.z), as_h2(k00.z), a2);
        a2 = __hfma2(as_h2(q0.w), as_h2(k00.w), a2);
        a2 = __hfma2(as_h2(q1.x), as_h2(k01.x), a2);
        a2 = __hfma2(as_h2(q1.y), as_h2(k01.y), a2);
        a2 = __hfma2(as_h2(q1.z), as_h2(k01.z), a2);
        a2 = __hfma2(as_h2(q1.w), as_h2(k01.w), a2);
        a2 = __hfma2(as_h2(q2.x), as_h2(k02.x), a2);
        a2 = __hfma2(as_h2(q2.y), as_h2(k02.y), a2);
        a2 = __hfma2(as_h2(q2.z), as_h2(k02.z), a2);
        a2 = __hfma2(as_h2(q2.w), as_h2(k02.w), a2);
        a2 = __hfma2(as_h2(q3.x), as_h2(k03.x), a2);
        a2 = __hfma2(as_h2(q3.y), as_h2(k03.y), a2);
        a2 = __hfma2(as_h2(q3.z), as_h2(k03.z), a2);
        a2 = __hfma2(as_h2(q3.w), as_h2(k03.w), a2);
        float acc = __half2float(__low2half(a2)) + __half2float(__high2half(a2));
        sc[0] = (msk == 0) ? -1e9f : acc * 0.17677669529663687f;
    }
    {
        const uint4* qr = (const uint4*)(&qrv[w][(hh2 + 2) * 16]);
        uint4 q0 = qr[0], q1 = qr[1], q2 = qr[2], q3 = qr[3];
        __half2 a2 = as_h2(0u);
        a2 = __hfma2(as_h2(q0.x), as_h2(k10.x), a2);
        a2 = __hfma2(as_h2(q0.y), as_h2(k10.y), a2);
        a2 = __hfma2(as_h2(q0.z), as_h2(k10.z), a2);
        a2 = __hfma2(as_h2(q0.w), as_h2(k10.w), a2);
        a2 = __hfma2(as_h2(q1.x), as_h2(k11.x), a2);
        a2 = __hfma2(as_h2(q1.y), as_h2(k11.y), a2);
        a2 = __hfma2(as_h2(q1.z), as_h2(k11.z), a2);
        a2 = __hfma2(as_h2(q1.w), as_h2(k11.w), a2);
        a2 = __hfma2(as_h2(q2.x), as_h2(k12.x), a2);
        a2 = __hfma2(as_h2(q2.y), as_h2(k12.y), a2);
        a2 = __hfma2(as_h2(q2.z), as_h2(k12.z), a2);
        a2 = __hfma2(as_h2(q2.w), as_h2(k12.w), a2);
        a2 = __hfma2(as_h2(q3.x), as_h2(k13.x), a2);
        a2 = __hfma2(as_h2(q3.y), as_h2(k13.y), a2);
        a2 = __hfma2(as_h2(q3.z), as_h2(k13.z), a2);
        a2 = __hfma2(as_h2(q3.w), as_h2(k13.w), a2);
        float acc = __half2float(__low2half(a2)) + __half2float(__high2half(a2));
        sc[1] = (msk == 0) ? -1e9f : acc * 0.17677669529663687f;
    }

    // ---- softmax over m (32-lane groups); alpha -> union LDS ----
#pragma unroll
    for (int hp = 0; hp < 2; ++hp) {
        float mx = sc[hp];
#pragma unroll
        for (int off = 1; off < 32; off <<= 1)
            mx = fmaxf(mx, __shfl_xor(mx, off));
        float e = __expf(sc[hp] - mx);
        float s = e;
#pragma unroll
        for (int off = 1; off < 32; off <<= 1)
            s += __shfl_xor(s, off);
        ufc[w][(hh2 + 2 * hp) * 33 + m] = e / s;
    }

    // ---- wait V staging, then PV from LDS (fp8 -> f32); lane = dim-pair ----
    asm volatile("s_waitcnt vmcnt(0)" ::: "memory");
    {
        const int hh = lane >> 4;            // head of dims 2*lane, 2*lane+1
        const uint sh = (lane & 1) ? 16u : 0u;
        float a0 = 0.f, a1 = 0.f;
#pragma unroll
        for (int mm = 0; mm < MAXN; ++mm) {
            uint u = vlds8[w][mm * 32 + (lane >> 1)];
            f32x2 vf = __builtin_amdgcn_cvt_pk_f32_fp8(u >> sh, false);
            float al = ufc[w][hh * 33 + mm];
            a0 = fmaf(al, vf.x, a0);
            a1 = fmaf(al, vf.y, a1);
        }
        // overwrite own wave's Q row (scores done with it)
        qrv[w][lane] = as_u(__floats2half2_rn(a0, a1));
    }
    __syncthreads();     // alpha reads done; ufc reused as fcout. rv visible to all.

    // ---- FC via MFMA; wave w = column tile w (8 real rows, 8 zero) ----
    {
        const int rl  = lane & 15;
        const int kb  = lane >> 4;
        const int col = 16 * w + rl;

        f32x4 acc = (f32x4){0.f, 0.f, 0.f, 0.f};
#pragma unroll
        for (int ks = 0; ks < 4; ++ks) {
            uint4 au = *(const uint4*)(&qrv[rl & 7][ks * 16 + kb * 4]);
            if (rl >= 8) au = (uint4){0u, 0u, 0u, 0u};
            f16x8 af = as_f16x8(au);
            f16x8 bfr = *(const f16x8*)(WfcT + (size_t)col * DIM + ks * 32 + kb * 8);
            acc = __builtin_amdgcn_mfma_f32_16x16x32_f16(af, bfr, acc, 0, 0, 0);
        }
        if (kb < 2) {
#pragma unroll
            for (int j = 0; j < 4; ++j) ufc[kb * 4 + j][col] = acc[j];
        }
    }
    __syncthreads();

    // ---- epilogue (wave-local): wave w = node w; cols {2*lane, 2*lane+1} ----
    {
        uint qu = ((const uint*)Qh)[(size_t)node * 64 + lane];   // residual (half2)
        __half2 qh2 = as_h2(qu);
        float2 bf2 = *(const float2*)(bfc + 2 * lane);
        float x0 = ufc[w][2 * lane]     + bf2.x + __half2float(__low2half(qh2));
        float x1 = ufc[w][2 * lane + 1] + bf2.y + __half2float(__high2half(qh2));
        float g0 = 0.5f * x0 * (1.0f + erff(x0 * 0.70710678118654752f));
        float g1 = 0.5f * x1 * (1.0f + erff(x1 * 0.70710678118654752f));

        float s1 = g0 + g1, s2 = g0 * g0 + g1 * g1;
#pragma unroll
        for (int off = 1; off < 64; off <<= 1) {
            s1 += __shfl_xor(s1, off);
            s2 += __shfl_xor(s2, off);
        }
        float mean = s1 * (1.0f / DIM);
        float var  = s2 * (1.0f / DIM) - mean * mean;
        float invs = rsqrtf(var + LN_EPS);

        float2 gm2 = *(const float2*)(gamma + 2 * lane);
        float2 bt2 = *(const float2*)(beta + 2 * lane);
        float2 o;
        o.x = (g0 - mean) * invs * gm2.x + bt2.x;
        o.y = (g1 - mean) * invs * gm2.y + bt2.y;
        *(float2*)(out + (size_t)node * DIM + 2 * lane) = o;
    }
}

extern "C" void kernel_launch(void* const* d_in, const int* in_sizes, int n_in,
                              void* d_out, int out_size, void* d_ws, size_t ws_size,
                              hipStream_t stream) {
    (void)in_sizes; (void)n_in; (void)out_size; (void)ws_size;
    const float* h     = (const float*)d_in[0];
    const float* Wq    = (const float*)d_in[1];
    const float* Wk    = (const float*)d_in[2];
    const float* Wv    = (const float*)d_in[3];
    const float* Wfc   = (const float*)d_in[4];
    const float* bfc   = (const float*)d_in[5];
    const float* gamma = (const float*)d_in[6];
    const float* beta  = (const float*)d_in[7];
    const int* nidx    = (const int*)d_in[8];
    const int* nmask   = (const int*)d_in[9];

    f16*   Kh   = (f16*)d_ws;
    f16*   Qh   = Kh + (size_t)N_NODES * DIM;
    uchar* V8   = (uchar*)(Qh + (size_t)N_NODES * DIM);
    f16*   WqT  = (f16*)(V8 + (size_t)N_NODES * DIM);
    f16*   WkT  = WqT + (size_t)DIM * DIM;
    f16*   WvT  = WkT + (size_t)DIM * DIM;
    f16*   WfcT = WvT + (size_t)DIM * DIM;

    prep_kernel<<<DIM, DIM, 0, stream>>>(Wq, Wk, Wv, Wfc, WqT, WkT, WvT, WfcT);
    qkv_mfma_kernel<<<(N_NODES + 63) / 64, 256, 0, stream>>>(h, WqT, WkT, WvT, Qh, Kh, V8);
    attn_fc_kernel<<<N_NODES / 8, 512, 0, stream>>>(Qh, Kh, V8, nidx, nmask,
                                                    WfcT, bfc, gamma, beta, (float*)d_out);
}

// Round 17
// 70.294 us; speedup vs baseline: 1.2565x; 1.2124x over previous
//
#include <hip/hip_runtime.h>
#include <hip/hip_fp16.h>
#include <math.h>

#define N_NODES 30000
#define MAXN 32
#define DIM 128
#define NHEAD 4
#define HDIM 32
#define LN_EPS 1e-5f

typedef _Float16 f16;
typedef unsigned char uchar;
typedef __attribute__((ext_vector_type(8))) _Float16 f16x8;
typedef __attribute__((ext_vector_type(4))) float f32x4;
typedef __attribute__((ext_vector_type(2))) float f32x2;

static __device__ __forceinline__ __half2 as_h2(uint u) { return __builtin_bit_cast(__half2, u); }
static __device__ __forceinline__ uint as_u(__half2 h) { return __builtin_bit_cast(uint, h); }
static __device__ __forceinline__ f16x8 as_f16x8(uint4 u) { return __builtin_bit_cast(f16x8, u); }

// async global->LDS gather, 16B per lane; dest = uniform base + lane*16
static __device__ __forceinline__ void async_ld16(const uint* g, uint* lds_base) {
    __builtin_amdgcn_global_load_lds(
        (const __attribute__((address_space(1))) void*)g,
        (__attribute__((address_space(3))) void*)lds_base,
        16, 0, 0);
}

// ---------------- prep: W[k][n] f32 -> WT[n][k] f16 for Wq,Wk,Wv,Wfc ----------------
__global__ __launch_bounds__(128) void prep_kernel(
    const float* __restrict__ Wq, const float* __restrict__ Wk,
    const float* __restrict__ Wv, const float* __restrict__ Wfc,
    f16* __restrict__ WqT, f16* __restrict__ WkT,
    f16* __restrict__ WvT, f16* __restrict__ WfcT)
{
    const int n = blockIdx.x, k = threadIdx.x;
    WqT[n * DIM + k]  = (f16)Wq[k * DIM + n];
    WkT[n * DIM + k]  = (f16)Wk[k * DIM + n];
    WvT[n * DIM + k]  = (f16)Wv[k * DIM + n];
    WfcT[n * DIM + k] = (f16)Wfc[k * DIM + n];
}

// ---------------- Kernel 1: QKV projection via MFMA, weights staged in LDS ----------------
// Q -> fp16; K,V -> fp8 e4m3 (256B/edge gather instead of 384B).
__global__ __launch_bounds__(256) void qkv_mfma_kernel(
    const float* __restrict__ h,
    const f16* __restrict__ WqT,
    const f16* __restrict__ WkT,
    const f16* __restrict__ WvT,
    f16* __restrict__ Qout,
    uchar* __restrict__ Kout8,
    uchar* __restrict__ Vout8)
{
    __shared__ f16 wlds[DIM][136];

    const int lane = threadIdx.x & 63;
    const int wid  = threadIdx.x >> 6;
    const int r0w  = blockIdx.x * 64 + wid * 16;
    const int rl = lane & 15;
    const int kb = lane >> 4;

    const int arow = min(r0w + rl, N_NODES - 1);
    const float* hrow = h + (size_t)arow * DIM + kb * 8;
    f16x8 a[4];
#pragma unroll
    for (int ks = 0; ks < 4; ++ks) {
        float4 f0 = *(const float4*)(hrow + ks * 32);
        float4 f1 = *(const float4*)(hrow + ks * 32 + 4);
        f16x8 v;
        v[0] = (f16)f0.x; v[1] = (f16)f0.y; v[2] = (f16)f0.z; v[3] = (f16)f0.w;
        v[4] = (f16)f1.x; v[5] = (f16)f1.y; v[6] = (f16)f1.z; v[7] = (f16)f1.w;
        a[ks] = v;
    }

    f32x4 acc[8];

#define STAGE_W(WT)                                                         \
    {                                                                       \
        const uint4* s4 = (const uint4*)(WT);                               \
        _Pragma("unroll")                                                   \
        for (int i = 0; i < 8; ++i) {                                       \
            int L = i * 256 + (int)threadIdx.x;                             \
            *(uint4*)(&wlds[L >> 4][(L & 15) * 8]) = s4[L];                 \
        }                                                                   \
    }

#define GEMM_LDS()                                                          \
    _Pragma("unroll")                                                       \
    for (int tc = 0; tc < 8; ++tc) acc[tc] = (f32x4){0.f, 0.f, 0.f, 0.f};   \
    _Pragma("unroll")                                                       \
    for (int ks = 0; ks < 4; ++ks) {                                        \
        _Pragma("unroll")                                                   \
        for (int tc = 0; tc < 8; ++tc) {                                    \
            f16x8 bfrag = *(const f16x8*)(&wlds[rl + 16 * tc][ks * 32 + kb * 8]); \
            acc[tc] = __builtin_amdgcn_mfma_f32_16x16x32_f16(a[ks], bfrag, acc[tc], 0, 0, 0); \
        }                                                                   \
    }

#define STORE_FP8(OUT)                                                      \
    _Pragma("unroll")                                                       \
    for (int j = 0; j < 4; ++j) {                                           \
        const int row = r0w + kb * 4 + j;                                   \
        if (row < N_NODES) {                                                \
            uchar* orow = (OUT) + (size_t)row * DIM;                        \
            _Pragma("unroll")                                               \
            for (int tc = 0; tc < 8; ++tc) {                                \
                uint r = (uint)__builtin_amdgcn_cvt_pk_fp8_f32(acc[tc][j], 0.f, 0, false); \
                orow[rl + 16 * tc] = (uchar)(r & 0xffu);                    \
            }                                                               \
        }                                                                   \
    }

    // ---- Q (fp16) ----
    STAGE_W(WqT);
    __syncthreads();
    GEMM_LDS();
#pragma unroll
    for (int j = 0; j < 4; ++j) {
        const int row = r0w + kb * 4 + j;
        if (row < N_NODES) {
            f16* orow = Qout + (size_t)row * DIM;
#pragma unroll
            for (int tc = 0; tc < 8; ++tc) orow[rl + 16 * tc] = (f16)acc[tc][j];
        }
    }
    __syncthreads();
    // ---- K (fp8) ----
    STAGE_W(WkT);
    __syncthreads();
    GEMM_LDS();
    STORE_FP8(Kout8);
    __syncthreads();
    // ---- V (fp8) ----
    STAGE_W(WvT);
    __syncthreads();
    GEMM_LDS();
    STORE_FP8(Vout8);
}

// ---------------- Kernel 2: fused gather-attention + FC + GELU + LN ----------------
// R14 structure: 512 threads = 8 waves = 8 nodes (1 node/wave), (512,6).
// K: fp8, 4 uint4 direct loads. V: fp8, 4 async global_load_lds per node.
__global__ __launch_bounds__(512, 6) void attn_fc_kernel(
    const f16* __restrict__ Qh,          // [N][128] fp16 (ws)
    const uchar* __restrict__ K8,        // [N][128] fp8 e4m3 (ws)
    const uchar* __restrict__ V8,        // [N][128] fp8 e4m3 (ws)
    const int* __restrict__ nidx,
    const int* __restrict__ nmask,
    const f16* __restrict__ WfcT,        // [n][k] fp16
    const float* __restrict__ bfc,
    const float* __restrict__ gamma,
    const float* __restrict__ beta,
    float* __restrict__ out)
{
    __shared__ uint  vlds8[8][1024];      // 32KB: V fp8 [node][32 rows x 128B]
    __shared__ uint  qsh[8][68];          // Q rows as half2
    __shared__ float al_f[8][NHEAD][33];  // alpha f32
    __shared__ uint  rv_u[8][68];         // attn-out rows as half2
    __shared__ float fcout[8][132];       // FC output (pre-bias)
    __shared__ int   idx_s[8][MAXN];

    const int t    = threadIdx.x;
    const int b    = blockIdx.x;
    const int w    = t >> 6;        // wave = node slot 0..7
    const int lane = t & 63;
    const int node = b * 8 + w;

    // ---- front-load independent memory ops ----
    const int m   = lane & 31;
    const int hh2 = lane >> 5;
    const int src = nidx[(size_t)node * MAXN + m];
    const int msk = nmask[(size_t)node * MAXN + m];
    qsh[w][lane] = ((const uint*)Qh)[(size_t)node * 64 + lane];
    if (lane < 32) idx_s[w][m] = src;

    // K loads (fp8, issued FIRST -> oldest in vmcnt queue); 32B per head slice
    const uint4* k8r0 = (const uint4*)(K8 + (size_t)src * DIM + hh2 * HDIM);
    const uint4* k8r1 = (const uint4*)(K8 + (size_t)src * DIM + (hh2 + 2) * HDIM);
    uint4 ka0 = k8r0[0], ka1 = k8r0[1];
    uint4 kb0 = k8r1[0], kb1 = k8r1[1];

    // V async staging (fp8, youngest): instr i covers rows i*8+(lane>>3), chunk lane&7.
    {
#pragma unroll
        for (int i = 0; i < 4; ++i) {
            int r = i * 8 + (lane >> 3);
            int c = lane & 7;
            const uint* gp = (const uint*)(V8 + (size_t)idx_s[w][r] * DIM + c * 16);
            async_ld16(gp, &vlds8[w][i * 256]);
        }
    }

    // ---- scores (fp8 K -> f32, Q from LDS); V staging stays in flight ----
    float sc[2];
#pragma unroll
    for (int hp = 0; hp < 2; ++hp) {
        const int hh = hh2 + 2 * hp;
        uint kw[8];
        if (hp == 0) {
            kw[0] = ka0.x; kw[1] = ka0.y; kw[2] = ka0.z; kw[3] = ka0.w;
            kw[4] = ka1.x; kw[5] = ka1.y; kw[6] = ka1.z; kw[7] = ka1.w;
        } else {
            kw[0] = kb0.x; kw[1] = kb0.y; kw[2] = kb0.z; kw[3] = kb0.w;
            kw[4] = kb1.x; kw[5] = kb1.y; kw[6] = kb1.z; kw[7] = kb1.w;
        }
        const uint* qu = &qsh[w][hh * 16];
        float acc = 0.f;
#pragma unroll
        for (int i = 0; i < 8; ++i) {
            f32x2 v01 = __builtin_amdgcn_cvt_pk_f32_fp8(kw[i], false);  // dims 4i,4i+1
            f32x2 v23 = __builtin_amdgcn_cvt_pk_f32_fp8(kw[i], true);   // dims 4i+2,4i+3
            float2 q01 = __half22float2(as_h2(qu[2 * i]));
            float2 q23 = __half22float2(as_h2(qu[2 * i + 1]));
            acc = fmaf(q01.x, v01.x, acc);
            acc = fmaf(q01.y, v01.y, acc);
            acc = fmaf(q23.x, v23.x, acc);
            acc = fmaf(q23.y, v23.y, acc);
        }
        sc[hp] = (msk == 0) ? -1e9f : acc * 0.17677669529663687f;
    }

    // ---- softmax over m (32-lane groups) ----
#pragma unroll
    for (int hp = 0; hp < 2; ++hp) {
        float mx = sc[hp];
#pragma unroll
        for (int off = 1; off < 32; off <<= 1)
            mx = fmaxf(mx, __shfl_xor(mx, off));
        float e = __expf(sc[hp] - mx);
        float s = e;
#pragma unroll
        for (int off = 1; off < 32; off <<= 1)
            s += __shfl_xor(s, off);
        al_f[w][hh2 + 2 * hp][m] = e / s;
    }

    // ---- wait V staging, then PV from LDS (fp8 -> f32); lane = dim-pair ----
    asm volatile("s_waitcnt vmcnt(0)" ::: "memory");
    {
        const int hh = lane >> 4;            // head of dims 2*lane, 2*lane+1
        const uint sh = (lane & 1) ? 16u : 0u;
        float a0 = 0.f, a1 = 0.f;
#pragma unroll
        for (int mm = 0; mm < MAXN; ++mm) {
            uint u = vlds8[w][mm * 32 + (lane >> 1)];
            f32x2 vf = __builtin_amdgcn_cvt_pk_f32_fp8(u >> sh, false);
            float al = al_f[w][hh][mm];
            a0 = fmaf(al, vf.x, a0);
            a1 = fmaf(al, vf.y, a1);
        }
        rv_u[w][lane] = as_u(__floats2half2_rn(a0, a1));
    }
    __syncthreads();

    // ---- FC via MFMA; wave w = column tile w (8 real rows, 8 zero) ----
    {
        const int rl  = lane & 15;
        const int kb  = lane >> 4;
        const int col = 16 * w + rl;

        f32x4 acc = (f32x4){0.f, 0.f, 0.f, 0.f};
#pragma unroll
        for (int ks = 0; ks < 4; ++ks) {
            uint4 au = *(const uint4*)(&rv_u[rl & 7][ks * 16 + kb * 4]);
            if (rl >= 8) au = (uint4){0u, 0u, 0u, 0u};
            f16x8 af = as_f16x8(au);
            f16x8 bfr = *(const f16x8*)(WfcT + (size_t)col * DIM + ks * 32 + kb * 8);
            acc = __builtin_amdgcn_mfma_f32_16x16x32_f16(af, bfr, acc, 0, 0, 0);
        }
        if (kb < 2) {
#pragma unroll
            for (int j = 0; j < 4; ++j) fcout[kb * 4 + j][col] = acc[j];
        }
    }
    __syncthreads();

    // ---- epilogue (wave-local): wave w = node w; 2 cols/lane; in-wave LN ----
    {
        float g2[2];
        float s1 = 0.f, s2 = 0.f;
#pragma unroll
        for (int p = 0; p < 2; ++p) {
            const int c = lane + 64 * p;
            __half2 qh2 = as_h2(qsh[w][c >> 1]);
            float qv = __half2float((c & 1) ? __high2half(qh2) : __low2half(qh2));
            float x = fcout[w][c] + bfc[c] + qv;
            float gg = 0.5f * x * (1.0f + erff(x * 0.70710678118654752f));
            g2[p] = gg;
            s1 += gg;
            s2 += gg * gg;
        }
#pragma unroll
        for (int off = 1; off < 64; off <<= 1) {
            s1 += __shfl_xor(s1, off);
            s2 += __shfl_xor(s2, off);
        }
        float mean = s1 * (1.0f / DIM);
        float var  = s2 * (1.0f / DIM) - mean * mean;
        float invs = rsqrtf(var + LN_EPS);
#pragma unroll
        for (int p = 0; p < 2; ++p) {
            const int c = lane + 64 * p;
            out[(size_t)node * DIM + c] = (g2[p] - mean) * invs * gamma[c] + beta[c];
        }
    }
}

extern "C" void kernel_launch(void* const* d_in, const int* in_sizes, int n_in,
                              void* d_out, int out_size, void* d_ws, size_t ws_size,
                              hipStream_t stream) {
    (void)in_sizes; (void)n_in; (void)out_size; (void)ws_size;
    const float* h     = (const float*)d_in[0];
    const float* Wq    = (const float*)d_in[1];
    const float* Wk    = (const float*)d_in[2];
    const float* Wv    = (const float*)d_in[3];
    const float* Wfc   = (const float*)d_in[4];
    const float* bfc   = (const float*)d_in[5];
    const float* gamma = (const float*)d_in[6];
    const float* beta  = (const float*)d_in[7];
    const int* nidx    = (const int*)d_in[8];
    const int* nmask   = (const int*)d_in[9];

    f16*   Qh   = (f16*)d_ws;
    uchar* K8   = (uchar*)(Qh + (size_t)N_NODES * DIM);
    uchar* V8   = K8 + (size_t)N_NODES * DIM;
    f16*   WqT  = (f16*)(V8 + (size_t)N_NODES * DIM);
    f16*   WkT  = WqT + (size_t)DIM * DIM;
    f16*   WvT  = WkT + (size_t)DIM * DIM;
    f16*   WfcT = WvT + (size_t)DIM * DIM;

    prep_kernel<<<DIM, DIM, 0, stream>>>(Wq, Wk, Wv, Wfc, WqT, WkT, WvT, WfcT);
    qkv_mfma_kernel<<<(N_NODES + 63) / 64, 256, 0, stream>>>(h, WqT, WkT, WvT, Qh, K8, V8);
    attn_fc_kernel<<<N_NODES / 8, 512, 0, stream>>>(Qh, K8, V8, nidx, nmask,
                                                    WfcT, bfc, gamma, beta, (float*)d_out);
}